// Round 10
// baseline (822.235 us; speedup 1.0000x reference)
//
#include <hip/hip_runtime.h>

#define BT 4096
#define H  2048
#define V  32000
#define BM 128
#define BN 128
#define BKB 128                   /* fp8 bytes per K-tile row */
#define KT (H / BKB)              /* 16 K-tiles */
#define NTILES (V / BN)           /* 250 */
#define MTILES (BT / BM)          /* 32 */
#define NWG (MTILES * NTILES)     /* 8000, % 8 == 0 -> bijective XCD swizzle */
#define IGNORE_INDEX (-100)

typedef int   v8i   __attribute__((ext_vector_type(8)));
typedef float f32x4 __attribute__((ext_vector_type(4)));

#define SCALE_ONE 0x7F7F7F7F        /* E8M0 127 = 2^0 in every byte */
#define UNSCALE   (1.0f / 65536.0f) /* inputs pre-scaled by 2^8 each */

#define BAR()   __builtin_amdgcn_s_barrier()
#define SB0()   __builtin_amdgcn_sched_barrier(0)
#define LGKM0() asm volatile("s_waitcnt lgkmcnt(0)" ::: "memory")
#define VMC(N)  asm volatile("s_waitcnt vmcnt(" #N ")" ::: "memory")

__device__ inline void load_lds16(const void* g, void* l) {
  __builtin_amdgcn_global_load_lds(
      (const __attribute__((address_space(1))) unsigned int*)g,
      (__attribute__((address_space(3))) unsigned int*)l,
      16, 0, 0);
}

// ------------------------------------------- fp32 -> fp8 e4m3, FRAG-PACKED
// Fused W+H conversion (one launch). Per task (row-group g, K-tile kt):
// coalesced 16x128-float load -> LDS transpose -> packed 2KB block:
//   byte [c*1024 + lane*16 + b] = fp8( in[g*16 + (lane&15)]
//                                       [kt*128 + (lane>>4)*32 + c*16 + b] )
// Block 0 also zeroes the loss accumulators used by rowlse_final.
#define W_TASKS ((V / 16) * KT)     /* 32000 */
#define H_TASKS ((BT / 16) * KT)    /* 4096  */
__global__ __launch_bounds__(256)
void cvt_pack_kernel(const float* __restrict__ wt, const float* __restrict__ hs,
                     unsigned char* __restrict__ wf8, unsigned char* __restrict__ hf8,
                     float* __restrict__ accbuf) {
  if (blockIdx.x == 0 && threadIdx.x == 0) {
    accbuf[0] = 0.f;                        // loss sum
    accbuf[1] = 0.f;                        // valid count
    ((unsigned*)accbuf)[2] = 0u;            // done counter
  }
  __shared__ float ld[4][16][132];          // stride 132: 2-way read (free)
  const int wv = threadIdx.x >> 6, lane = threadIdx.x & 63;
  int task = blockIdx.x * 4 + wv;
  if (task >= W_TASKS + H_TASKS) return;    // wave-divergent ok: no block bar
  const float* in = wt;
  unsigned char* out = wf8;
  if (task >= W_TASKS) { task -= W_TASKS; in = hs; out = hf8; }
  const int g = task >> 4, kt = task & 15;  // KT = 16
  const float* src = in + (size_t)(g * 16) * H + kt * 128;
#pragma unroll
  for (int i = 0; i < 8; ++i) {             // 512 float4, coalesced
    int idx = i * 64 + lane;
    int r = idx >> 5, c = idx & 31;
    float4 v = *(const float4*)(src + (size_t)r * H + c * 4);
    *(float4*)&ld[wv][r][c * 4] = v;
  }
  LGKM0();                                  // cross-lane LDS visibility
  const int row = lane & 15, kb = (lane >> 4) * 32;
  int p[8];
#pragma unroll
  for (int u = 0; u < 8; ++u) {
    float4 x = *(const float4*)&ld[wv][row][kb + u * 4];
    int v = 0;
    v = __builtin_amdgcn_cvt_pk_fp8_f32(x.x * 256.f, x.y * 256.f, v, false);
    v = __builtin_amdgcn_cvt_pk_fp8_f32(x.z * 256.f, x.w * 256.f, v, true);
    p[u] = v;
  }
  unsigned char* dst = out + ((size_t)g * KT + kt) * 2048 + lane * 16;
  int4 lo; lo.x = p[0]; lo.y = p[1]; lo.z = p[2]; lo.w = p[3];
  int4 hi; hi.x = p[4]; hi.y = p[5]; hi.z = p[6]; hi.w = p[7];
  *(int4*)dst          = lo;                // plane c=0
  *(int4*)(dst + 1024) = hi;                // plane c=1
}

// --------------------------------------------------------------------------
// 128x128-tile, 4-wave (2x2), 64x64 per wave, MX-fp8 16x16x128 MFMA.
// Memory plan (proven R3/R9: FETCH ~10MB, 0 conflicts): packed operands,
// contiguous-1KB global_load_lds, linear frag-contiguous LDS, frag read =
// base + lane*16 (+1024).
// Occupancy plan R10: LDS 68KB/block -> TWO INDEPENDENT blocks per CU
// (same 2 waves/SIMD as R5-R9, but desynced barriers: when one block sits
// in its VMC/BAR drain, the other feeds the MFMA/LDS pipes - m114).
// R7/R8 showed 4 waves/SIMD spills; this gets the overlap without the
// register cap. Per-wave code = R9's validated reg-pipelined 64x64 shape
// (VGPR 112, no spill).
// Phase per K-tile kt (buf b = kt&1, reg sets X/Y alternate):
//   stage(buf[b], kt+2); ds_read frags(kt+1)<-buf[b^1]; 16 MFMA(kt) from
//   regs; LGKM0; VMC(0); BAR.   (hazard ledger identical to R9 - proven)
// --------------------------------------------------------------------------
union frag_u { v8i v; int4 h[2]; };

#define MF(C, A, B)                                                         \
  (C) = __builtin_amdgcn_mfma_scale_f32_16x16x128_f8f6f4(                   \
      (A).v, (B).v, (C), 0, 0, 0, SCALE_ONE, 0, SCALE_ONE)

__global__ __launch_bounds__(256, 2)
void gemm_lse_kernel(const unsigned char* __restrict__ Af8,
                     const unsigned char* __restrict__ Bf8,
                     const int* __restrict__ tgt,
                     float* __restrict__ pm, float* __restrict__ pl,
                     float* __restrict__ tl) {
  __shared__ __align__(16) unsigned char As[2 * 16384];  // 32 KB (8 groups)
  __shared__ __align__(16) unsigned char Bs[2 * 16384];  // 32 KB (8 groups)
  __shared__ float red_m[2][BM];
  __shared__ float red_l[2][BM];
  __shared__ int   stgt[BM];

  // T1 bijective XCD swizzle (8000 % 8 == 0), mt fastest within an XCD:
  // 32 consecutive blocks share one 256KB B-panel (L2-resident); A via L2/L3.
  const int wgid = ((int)blockIdx.x & 7) * (NWG / 8) + ((int)blockIdx.x >> 3);
  const int mt = wgid & (MTILES - 1);
  const int nt = wgid >> 5;          // 0..249
  const int m0 = mt * BM;
  const int n0 = nt * BN;

  const int tid  = threadIdx.x;
  const int lane = tid & 63;
  const int w    = tid >> 6;   // wave 0..3
  const int wr   = w >> 1;     // 0..1 : rows [wr*64, +64)
  const int wc   = w & 1;      // 0..1 : cols [wc*64, +64)
  const int lm   = lane & 15;
  const int q    = lane >> 4;

  if (tid < BM) stgt[tid] = tgt[m0 + tid];
  __syncthreads();  // drains vmcnt before counted staging begins

  // packed sources; wave w stages A groups {2w,2w+1} and B groups {2w,2w+1}.
  const unsigned char* aSrc = Af8 + (size_t)(m0 / 16) * KT * 2048;
  const unsigned char* bSrc = Bf8 + (size_t)(n0 / 16) * KT * 2048;

  auto stage = [&](int buf, int kt) {    // 8 gloads per wave
#pragma unroll
    for (int e = 0; e < 2; ++e) {
      const int g = 2 * w + e;
      const unsigned char* sa = aSrc + ((size_t)g * KT + kt) * 2048;
      unsigned char* da = As + buf * 16384 + g * 2048;
      load_lds16(sa, da);
      load_lds16(sa + 1024, da + 1024);
      const unsigned char* sb = bSrc + ((size_t)g * KT + kt) * 2048;
      unsigned char* db = Bs + buf * 16384 + g * 2048;
      load_lds16(sb, db);
      load_lds16(sb + 1024, db + 1024);
    }
  };

  // fragment reads: per-lane address + immediate offsets (conflict-free).
  const unsigned char* aRd = As + (wr * 4) * 2048 + lane * 16;
  const unsigned char* bRd = Bs + (wc * 4) * 2048 + lane * 16;

  auto ldA = [&](frag_u& f, int buf, int i) {
    const unsigned char* p = aRd + buf * 16384 + i * 2048;
    f.h[0] = *(const int4*)(p);
    f.h[1] = *(const int4*)(p + 1024);
  };
  auto ldB = [&](frag_u& f, int buf, int j) {
    const unsigned char* p = bRd + buf * 16384 + j * 2048;
    f.h[0] = *(const int4*)(p);
    f.h[1] = *(const int4*)(p + 1024);
  };

  f32x4 acc[4][4];
#pragma unroll
  for (int a = 0; a < 4; ++a)
#pragma unroll
    for (int b = 0; b < 4; ++b) acc[a][b] = (f32x4){0.f, 0.f, 0.f, 0.f};

  frag_u faX[4], fbX[4], faY[4], fbY[4];   // two named frag sets (rule #20)

#define LDSET(SET, BUF)                                                     \
  ldA(fa##SET[0], BUF, 0); ldA(fa##SET[1], BUF, 1);                         \
  ldA(fa##SET[2], BUF, 2); ldA(fa##SET[3], BUF, 3);                         \
  ldB(fb##SET[0], BUF, 0); ldB(fb##SET[1], BUF, 1);                         \
  ldB(fb##SET[2], BUF, 2); ldB(fb##SET[3], BUF, 3);

#define MFSET(SET)                                                          \
  __builtin_amdgcn_s_setprio(1);                                            \
  MF(acc[0][0], fa##SET[0], fb##SET[0]); MF(acc[1][0], fa##SET[1], fb##SET[0]); \
  MF(acc[2][0], fa##SET[2], fb##SET[0]); MF(acc[3][0], fa##SET[3], fb##SET[0]); \
  MF(acc[0][1], fa##SET[0], fb##SET[1]); MF(acc[1][1], fa##SET[1], fb##SET[1]); \
  MF(acc[2][1], fa##SET[2], fb##SET[1]); MF(acc[3][1], fa##SET[3], fb##SET[1]); \
  MF(acc[0][2], fa##SET[0], fb##SET[2]); MF(acc[1][2], fa##SET[1], fb##SET[2]); \
  MF(acc[2][2], fa##SET[2], fb##SET[2]); MF(acc[3][2], fa##SET[3], fb##SET[2]); \
  MF(acc[0][3], fa##SET[0], fb##SET[3]); MF(acc[1][3], fa##SET[1], fb##SET[3]); \
  MF(acc[2][3], fa##SET[2], fb##SET[3]); MF(acc[3][3], fa##SET[3], fb##SET[3]); \
  __builtin_amdgcn_s_setprio(0);

  // ---- prologue: buf0 <- kt0; capture X <- buf0; buf1 <- kt1
  stage(0, 0);
  VMC(0); SB0(); BAR(); SB0();
  stage(1, 1);
  LDSET(X, 0)                          // kt0 frags -> X
  LGKM0(); VMC(0); SB0(); BAR(); SB0();

  for (int it = 0; it < 8; ++it) {
    const bool pre = (it < 7);

    // ---- phase kt = 2it: MFMA(X), prefetch Y <- buf1 (kt+1), stage buf0
    if (pre) stage(0, 2 * it + 2);
    LDSET(Y, 1)                        // kt+1 frags, hide under MFMAs
    MFSET(X)
    LGKM0(); VMC(0); SB0(); BAR(); SB0();

    // ---- phase kt+1: MFMA(Y), prefetch X <- buf0 (kt+2), stage buf1
    if (pre) {
      stage(1, 2 * it + 3);
      LDSET(X, 0)                      // kt+2 frags
    }
    MFSET(Y)
    LGKM0(); VMC(0); SB0(); BAR(); SB0();
  }

  __syncthreads();

  // ---- target-logit extraction (C layout: col=lane&15, row=q*4+reg)
#pragma unroll
  for (int ai = 0; ai < 4; ++ai) {
#pragma unroll
    for (int r = 0; r < 4; ++r) {
      int row_local = wr * 64 + ai * 16 + q * 4 + r;
      int c = stgt[row_local] - n0 - wc * 64;
      if ((unsigned)c < 64u && (c & 15) == lm) {
        int bj = c >> 4;
        float v = bj == 0 ? acc[ai][0][r]
                : bj == 1 ? acc[ai][1][r]
                : bj == 2 ? acc[ai][2][r]
                :           acc[ai][3][r];
        tl[m0 + row_local] = v * UNSCALE;
      }
    }
  }

  // ---- per-row (max, sumexp) over this wave's 64 columns
#pragma unroll
  for (int ai = 0; ai < 4; ++ai) {
#pragma unroll
    for (int r = 0; r < 4; ++r) {
      float v0 = acc[ai][0][r] * UNSCALE;
      float v1 = acc[ai][1][r] * UNSCALE;
      float v2 = acc[ai][2][r] * UNSCALE;
      float v3 = acc[ai][3][r] * UNSCALE;
      float mx = fmaxf(fmaxf(v0, v1), fmaxf(v2, v3));
#pragma unroll
      for (int off = 1; off < 16; off <<= 1) mx = fmaxf(mx, __shfl_xor(mx, off));
      float s = __expf(v0 - mx) + __expf(v1 - mx) + __expf(v2 - mx) + __expf(v3 - mx);
#pragma unroll
      for (int off = 1; off < 16; off <<= 1) s += __shfl_xor(s, off);
      if (lm == 0) {
        int row_local = wr * 64 + ai * 16 + q * 4 + r;
        red_m[wc][row_local] = mx;
        red_l[wc][row_local] = s;
      }
    }
  }
  __syncthreads();
  if (tid < BM) {
    float ma = red_m[0][tid], mb = red_m[1][tid];
    float M = fmaxf(ma, mb);
    float L = red_l[0][tid] * __expf(ma - M) + red_l[1][tid] * __expf(mb - M);
    long idx = (long)nt * BT + (m0 + tid);
    pm[idx] = M;
    pl[idx] = L;
  }
}

// ---------------------- combine partials + final mean (fused, last-block)
__global__ __launch_bounds__(256)
void rowlse_final_kernel(const float* __restrict__ pm, const float* __restrict__ pl,
                         const float* __restrict__ tl, const int* __restrict__ tgt,
                         float* __restrict__ accbuf, float* __restrict__ out) {
  __shared__ float sl[4], sc2[4];
  int wv   = threadIdx.x >> 6;
  int row  = blockIdx.x * 4 + wv;
  int lane = threadIdx.x & 63;
  float M = -__builtin_inff();
  float L = 0.f;
  for (int t = lane; t < NTILES; t += 64) {
    float m2 = pm[(long)t * BT + row];
    float l2 = pl[(long)t * BT + row];
    float Mn = fmaxf(M, m2);
    L = L * __expf(M - Mn) + l2 * __expf(m2 - Mn);
    M = Mn;
  }
#pragma unroll
  for (int off = 1; off < 64; off <<= 1) {
    float m2 = __shfl_xor(M, off);
    float l2 = __shfl_xor(L, off);
    float Mn = fmaxf(M, m2);
    L = L * __expf(M - Mn) + l2 * __expf(m2 - Mn);
    M = Mn;
  }
  if (lane == 0) {
    int t = tgt[row];
    bool valid = (t != IGNORE_INDEX);
    sl[wv]  = valid ? (M + logf(L) - tl[row]) : 0.f;
    sc2[wv] = valid ? 1.f : 0.f;
  }
  __syncthreads();
  if (threadIdx.x == 0) {
    atomicAdd(&accbuf[0], sl[0] + sl[1] + sl[2] + sl[3]);
    atomicAdd(&accbuf[1], sc2[0] + sc2[1] + sc2[2] + sc2[3]);
    __threadfence();
    unsigned t = atomicAdd((unsigned*)accbuf + 2, 1u);
    if (t == gridDim.x - 1) {
      float S = atomicAdd(&accbuf[0], 0.f);   // device-scope read
      float C = atomicAdd(&accbuf[1], 0.f);
      out[0] = S / fmaxf(C, 1.f);
    }
  }
}

extern "C" void kernel_launch(void* const* d_in, const int* in_sizes, int n_in,
                              void* d_out, int out_size, void* d_ws, size_t ws_size,
                              hipStream_t stream) {
  const float* hs  = (const float*)d_in[0];   // hidden_states [BT][H] fp32
  const float* wt  = (const float*)d_in[1];   // weight [V][H] fp32
  const int*   tgt = (const int*)d_in[2];     // targets [BT]
  float*       out = (float*)d_out;

  char* ws = (char*)d_ws;
  size_t off = 0;
  auto alloc = [&](size_t bytes) -> void* {
    void* p = ws + off;
    off += (bytes + 255) & ~(size_t)255;
    return p;
  };
  unsigned char* wf8 = (unsigned char*)alloc((size_t)V * H);        // 65.5 MB packed
  unsigned char* hf8 = (unsigned char*)alloc((size_t)BT * H);       // 8.4 MB packed
  float* pm = (float*)alloc((size_t)NTILES * BT * 4);               // 4.1 MB
  float* pl = (float*)alloc((size_t)NTILES * BT * 4);               // 4.1 MB
  float* tl = (float*)alloc((size_t)BT * 4);
  float* accbuf = (float*)alloc(256);                               // S, C, done
  (void)ws_size; (void)in_sizes; (void)n_in; (void)out_size;

  cvt_pack_kernel<<<(W_TASKS + H_TASKS) / 4, 256, 0, stream>>>(wt, hs, wf8, hf8, accbuf);
  gemm_lse_kernel<<<NWG, 256, 0, stream>>>(hf8, wf8, tgt, pm, pl, tl);
  rowlse_final_kernel<<<BT / 4, 256, 0, stream>>>(pm, pl, tl, tgt, accbuf, out);
}